// Round 17
// baseline (152.855 us; speedup 1.0000x reference)
//
#include <hip/hip_runtime.h>

#define NRES  300
#define NTRJ  20
#define NBINS 34
#define PLANE (NTRJ * NRES * 3)      // 18000 floats per output plane
#define NPP   75                     // CB partial planes (O: another 75)
#define OFF_H 150                    // H planes 150..169
#define NRED  ((PLANE + 255) / 256)  // 71

#define EXP2F(x) __builtin_exp2f(x)
#define LOG2F(x) __builtin_log2f(x)

// sum over the 16-lane jsub group (masks 1,2,4,8 stay within the group)
__device__ __forceinline__ float g16sum(float v) {
#pragma unroll
  for (int m = 1; m < 16; m <<= 1) v += __shfl_xor(v, m, 64);
  return v;
}

// R14 structure (best measured) with IC=1 for 2x wave count:
// 1500 blocks = (i 0..299) x (jt 0..4); 4 waves x [bsub 0..3 | jsub 0..15];
// each lane owns (j, 5 b's). Wave-private barrier-free gw staging (contiguous
// 16-row tile -> LDS padded rows -> 9 ds_read_b128). CB+O accumulate in
// registers across q; per-block CB/O results atomicAdd into ch%75 partial
// planes (4 writers/cell, pre-zeroed). H: in-loop 16-lane shuffle sum ->
// plain store into per-(jt,wave) plane. 4 exps per q (mB,mC derived from mA).
template <bool PART>
__global__ __launch_bounds__(256)
void force_fused(const float* __restrict__ cO, const float* __restrict__ cCB,
                 const float* __restrict__ cH, const float* __restrict__ gw,
                 const float* __restrict__ hmin, const float* __restrict__ hmax,
                 float* __restrict__ out, float* __restrict__ part) {
  __shared__ __align__(16) float wlds[4][16 * 36];   // per-wave padded w tiles
  __shared__ float sIC[NTRJ * 4];                    // i-side CB coords [b][4]
  __shared__ float sHH[NTRJ * 4];                    // i-side H coords

  const int tid  = threadIdx.x;
  const int wv   = tid >> 6;
  const int lane = tid & 63;
  const int bsub = lane >> 4;
  const int jsub = lane & 15;
  const int jt   = blockIdx.x % 5;
  const int i    = blockIdx.x / 5;          // one i per block (IC=1)
  const int j0w  = jt * 64 + wv * 16;
  const int j    = j0w + jsub;
  const bool jv  = (j < NRES);
  const int jc   = jv ? j : NRES - 1;
  const int E2   = 17 * min(16, max(0, NRES - j0w));

  if (tid < NTRJ * 3) {
    const int b = tid / 3, c = tid % 3;
    sIC[b * 4 + c] = cCB[(b * NRES + i) * 3 + c];
    sHH[b * 4 + c] = cH [(b * NRES + i) * 3 + c];
  }
  __syncthreads();

  // j-side coords for this lane's 5 trajectories
  float pjx[5], pjy[5], pjz[5], pox[5], poy[5], poz[5];
#pragma unroll
  for (int q = 0; q < 5; ++q) {
    const int b = bsub * 5 + q;
    const float* p = cCB + ((size_t)(b * NRES + jc)) * 3;
    pjx[q] = p[0]; pjy[q] = p[1]; pjz[q] = p[2];
    const float* o = cO + ((size_t)(b * NRES + jc)) * 3;
    pox[q] = o[0]; poy[q] = o[1]; poz[q] = o[2];
  }

  // load wave's 16 gw rows (contiguous 272 float2), stage into padded LDS rows
  float2 r2[5];
  {
    const float2* src = (const float2*)gw + ((size_t)i * NRES + j0w) * 17;
#pragma unroll
    for (int u = 0; u < 5; ++u) {
      const int e = lane + u * 64;
      r2[u] = (e < E2) ? src[e] : make_float2(0.f, 0.f);
    }
  }
  {
    float2* wd = (float2*)&wlds[wv][0];
#pragma unroll
    for (int u = 0; u < 5; ++u) {
      const int e = lane + u * 64;
      if (e < 272) {
        const int row = e / 17, col = e - row * 17;
        wd[row * 18 + col] = r2[u];   // padded to 18 float2 per row
      }
    }
  }

  // my j's weights: 9 x ds_read_b128 (DS pipe in-order per wave -> no barrier)
  float w[36];
  {
    const float4* wp = (const float4*)&wlds[wv][jsub * 36];
#pragma unroll
    for (int k4 = 0; k4 < 9; ++k4) {
      float4 v = wp[k4];
      w[4*k4+0] = v.x; w[4*k4+1] = v.y; w[4*k4+2] = v.z; w[4*k4+3] = v.w;
    }
    w[34] = 0.f; w[35] = 0.f;
  }

  const float hmn = hmin[i * NRES + jc];
  const float hmx = hmax[i * NRES + jc];

  float acx[5], acy[5], acz[5], aox[5], aoy[5], aoz[5];

#pragma unroll
  for (int q = 0; q < 5; ++q) {
    const int b = bsub * 5 + q;
    const float* pi = &sIC[b * 4];
    const float* ph = &sHH[b * 4];

    // ---- CB distogram: 3 x 12-bin ratio-recurrence, 4 exps total ----
    float dx = pjx[q] - pi[0], dy = pjy[q] - pi[1], dz = pjz[q] - pi[2];
    float d2 = fmaf(dx, dx, fmaf(dy, dy, dz * dz));
    d2 = fminf(fmaxf(d2, 0.01f), 1600.0f);          // d in [0.1, 40]
    float rinv = __frsqrt_rn(d2);
    float d    = d2 * rinv;
    float dA = d - 3.75f, dB = d - 9.75f, dC = d - 15.75f;
    // g_X = exp(-0.32 dX^2); m_A = exp(0.32 dA - 0.08); m_B = m_A e^-1.92;
    // m_C = m_A e^-3.84; per step m *= e^-0.16
    float gA = EXP2F(-0.46166241f * dA * dA);
    float gB = EXP2F(-0.46166241f * dB * dB);
    float gC = EXP2F(-0.46166241f * dC * dC);
    float mA = EXP2F(fmaf(0.46166241f, dA, -0.11541560f));
    float mB = mA * 0.14660697f;
    float mC = mA * 0.02149329f;
    float s0 = 0.f, s1 = 0.f, s2 = 0.f;
#pragma unroll
    for (int k = 0; k < 12; ++k) {
      s0 = fmaf(w[k]      * dA, gA, s0); gA *= mA; mA *= 0.85214379f; dA -= 0.5f;
      s1 = fmaf(w[k + 12] * dB, gB, s1); gB *= mB; mB *= 0.85214379f; dB -= 0.5f;
      s2 = fmaf(w[k + 24] * dC, gC, s2); gC *= mC; mC *= 0.85214379f; dC -= 0.5f;
    }
    float cf = 76.8f * ((s0 + s1) + s2) * rinv;     // 150 / sigma^3
    acx[q] = cf * dx; acy[q] = cf * dy; acz[q] = cf * dz;

    // ---- HB restraint (O_j - H_i) ----
    float ex = pox[q] - ph[0], ey = poy[q] - ph[1], ez = poz[q] - ph[2];
    float e2 = fmaf(ex, ex, fmaf(ey, ey, ez * ez));
    e2 = fminf(fmaxf(e2, 0.01f), 1600.0f);
    float rh = __frsqrt_rn(e2);
    float dh = e2 * rh;
    float vmin = fmaxf(hmn - dh, 0.0f);
    float vmax = fmaxf(dh - hmx, 0.0f);
    float fmn = 15.0f * vmin;                       // 3*5*v^1
    float fmx = (vmax > 0.0f) ? 5.0f * EXP2F(0.75f * LOG2F(vmax)) : 0.0f;
    float ff = (fmn - fmx) * rh;
    float qx = ff * ex, qy = ff * ey, qz = ff * ez; // pair_hb
    aox[q] = qx; aoy[q] = qy; aoz[q] = qz;

    // accs_H[b,i] = -sum_j pair_hb: 16-lane group sum, one plain store
    float sx = g16sum(jv ? qx : 0.f);
    float sy = g16sum(jv ? qy : 0.f);
    float sz = g16sum(jv ? qz : 0.f);
    if (jsub == 0) {
      if constexpr (PART) {
        float* hp = part + (size_t)(OFF_H + jt * 4 + wv) * PLANE +
                    ((size_t)b * NRES + i) * 3;
        hp[0] = -sx; hp[1] = -sy; hp[2] = -sz;
      } else {
        atomicAdd(&out[4 * PLANE + (b * NRES + i) * 3 + 0], -sx);
        atomicAdd(&out[4 * PLANE + (b * NRES + i) * 3 + 1], -sy);
        atomicAdd(&out[4 * PLANE + (b * NRES + i) * 3 + 2], -sz);
      }
    }
  }

  if (jv) {
    if constexpr (PART) {
      // 4 i-writers per cell (i % 75) -> negligible contention, pre-zeroed ws
      float* pc  = part + (size_t)(i % NPP) * PLANE;
      float* po2 = part + (size_t)(NPP + i % NPP) * PLANE;
#pragma unroll
      for (int q = 0; q < 5; ++q) {
        const int base = ((bsub * 5 + q) * NRES + j) * 3;
        atomicAdd(&pc[base + 0],  acx[q]);
        atomicAdd(&pc[base + 1],  acy[q]);
        atomicAdd(&pc[base + 2],  acz[q]);
        atomicAdd(&po2[base + 0], aox[q]);
        atomicAdd(&po2[base + 1], aoy[q]);
        atomicAdd(&po2[base + 2], aoz[q]);
      }
    } else {
#pragma unroll
      for (int q = 0; q < 5; ++q) {
        const int base = ((bsub * 5 + q) * NRES + j) * 3;
        atomicAdd(&out[3 * PLANE + base + 0], acx[q]);
        atomicAdd(&out[3 * PLANE + base + 1], acy[q]);
        atomicAdd(&out[3 * PLANE + base + 2], acz[q]);
        atomicAdd(&out[2 * PLANE + base + 0], aox[q]);
        atomicAdd(&out[2 * PLANE + base + 1], aoy[q]);
        atomicAdd(&out[2 * PLANE + base + 2], aoz[q]);
      }
    }
  }
}

// 7 segments x NRED blocks: 0-2 CB (25 planes each, atomic into out),
// 3-5 O (25 each, atomic), 6 H (20 planes, plain store).
__global__ __launch_bounds__(256)
void reduce_seg(const float* __restrict__ part, float* __restrict__ out) {
  const int seg = blockIdx.x / NRED;
  const int t   = (blockIdx.x % NRED) * 256 + threadIdx.x;
  if (t >= PLANE) return;

  if (seg < 6) {
    const int c0 = (seg < 3) ? seg * 25 : NPP + (seg - 3) * 25;
    const float* p = part + t + (size_t)c0 * PLANE;
    float s[5] = {};
#pragma unroll
    for (int c = 0; c < 25; c += 5) {
#pragma unroll
      for (int u = 0; u < 5; ++u) s[u] += p[(size_t)(c + u) * PLANE];
    }
    const float tot = ((s[0] + s[1]) + (s[2] + s[3])) + s[4];
    atomicAdd(&out[((seg < 3) ? 3 : 2) * PLANE + t], tot);
  } else {
    const float* p = part + t + (size_t)OFF_H * PLANE;
    float s[5] = {};
#pragma unroll
    for (int c = 0; c < 20; c += 5) {
#pragma unroll
      for (int u = 0; u < 5; ++u) s[u] += p[(size_t)(c + u) * PLANE];
    }
    out[4 * PLANE + t] = ((s[0] + s[1]) + (s[2] + s[3])) + s[4];
  }
}

extern "C" void kernel_launch(void* const* d_in, const int* in_sizes, int n_in,
                              void* d_out, int out_size, void* d_ws, size_t ws_size,
                              hipStream_t stream) {
  // input order per setup_inputs(): N, C, O, CB, H, gaussian_weights, hb_min, hb_max
  const float* cO  = (const float*)d_in[2];
  const float* cCB = (const float*)d_in[3];
  const float* cH  = (const float*)d_in[4];
  const float* gw  = (const float*)d_in[5];
  const float* hmn = (const float*)d_in[6];
  const float* hmx = (const float*)d_in[7];
  float* out  = (float*)d_out;
  float* part = (float*)d_ws;

  const size_t need = (size_t)(OFF_H + 20) * PLANE * sizeof(float);  // 12.24 MB

  // out zeroed every call: N,C planes are exactly 0 (K_ANG_HB_GEN==0) and
  // reduce atomics accumulate into CB/O planes.
  (void)hipMemsetAsync(out, 0, (size_t)out_size * sizeof(float), stream);

  if (ws_size >= need) {
    // zero only the atomically-accumulated CB/O partial region (10.8 MB)
    (void)hipMemsetAsync(part, 0, (size_t)2 * NPP * PLANE * sizeof(float), stream);
    force_fused<true><<<dim3(5 * NRES), dim3(256), 0, stream>>>(
        cO, cCB, cH, gw, hmn, hmx, out, part);
    reduce_seg<<<dim3(7 * NRED), dim3(256), 0, stream>>>(part, out);
  } else {
    force_fused<false><<<dim3(5 * NRES), dim3(256), 0, stream>>>(
        cO, cCB, cH, gw, hmn, hmx, out, nullptr);
  }
}

// Round 18
// 43.424 us; speedup vs baseline: 3.5201x; 3.5201x over previous
//
#include <hip/hip_runtime.h>

#define NRES  300
#define NTRJ  20
#define NBINS 34
#define PLANE (NTRJ * NRES * 3)      // 18000 floats per output plane
#define NCH   150                    // i-chunks of 2
#define OFF_O 150                    // O partial planes 150..299
#define OFF_H 300                    // H partial planes 300..319
#define NPL   320                    // 23.04 MB (R14-proven available)
#define NRED  ((PLANE + 255) / 256)  // 71

#define EXP2F(x) __builtin_exp2f(x)
#define LOG2F(x) __builtin_log2f(x)

// sum over the 16-lane jsub group (masks 1,2,4,8 stay within the group)
__device__ __forceinline__ float g16sum(float v) {
#pragma unroll
  for (int m = 1; m < 16; m <<= 1) v += __shfl_xor(v, m, 64);
  return v;
}

// 750 blocks x 512 threads (8 waves): wave = (h = i-half, s = j-slot).
// Each wave: ONE i = 2*ch+h, 16 j's = jt*64+s*16.., all 20 b (bsub*5+q).
// Wave-private barrier-free gw staging (16 contiguous rows -> padded LDS ->
// 9 ds_read_b128). CB/O combined across the h-pair via one-barrier LDS
// exchange, then PLAIN stores to per-chunk planes (zero hot-path atomics --
// R17 lesson: every device atomic is an HBM round-trip). H: 16-lane shuffle
// sum -> plain store into per-(jt,s) plane (h-halves hit disjoint cells).
template <bool PART>
__global__ __launch_bounds__(512)
void force_fused(const float* __restrict__ cO, const float* __restrict__ cCB,
                 const float* __restrict__ cH, const float* __restrict__ gw,
                 const float* __restrict__ hmin, const float* __restrict__ hmax,
                 float* __restrict__ out, float* __restrict__ part) {
  __shared__ __align__(16) float wlds[8][16 * 36];   // 18.4 KB w tiles
  __shared__ float cbuf[4][64][30];                  // 30.7 KB combine buffer
  __shared__ float sIC[NTRJ * 2 * 4];                // i-side CB coords
  __shared__ float sHH[NTRJ * 2 * 4];                // i-side H coords

  const int tid  = threadIdx.x;
  const int wv   = tid >> 6;
  const int lane = tid & 63;
  const int h    = wv >> 2;                 // i-half 0/1
  const int s    = wv & 3;                  // j-slot 0..3
  const int bsub = lane >> 4;
  const int jsub = lane & 15;
  const int jt   = blockIdx.x % 5;
  const int ch   = blockIdx.x / 5;          // 0..149
  const int i0   = ch * 2;
  const int i    = i0 + h;
  const int j0w  = jt * 64 + s * 16;
  const int j    = j0w + jsub;
  const bool jv  = (j < NRES);
  const int jc   = jv ? j : NRES - 1;
  const int E2   = 17 * min(16, max(0, NRES - j0w));

  // stage i-side coords for both halves: [b][ii][4]
  for (int e = tid; e < NTRJ * 2 * 3; e += 512) {
    const int b = e / 6, r = e % 6, ii = r / 3, c = r % 3;
    sIC[(b * 2 + ii) * 4 + c] = cCB[(b * NRES + i0 + ii) * 3 + c];
    sHH[(b * 2 + ii) * 4 + c] = cH [(b * NRES + i0 + ii) * 3 + c];
  }
  __syncthreads();

  // j-side coords for this lane's 5 trajectories
  float pjx[5], pjy[5], pjz[5], pox[5], poy[5], poz[5];
#pragma unroll
  for (int q = 0; q < 5; ++q) {
    const int b = bsub * 5 + q;
    const float* p = cCB + ((size_t)(b * NRES + jc)) * 3;
    pjx[q] = p[0]; pjy[q] = p[1]; pjz[q] = p[2];
    const float* o = cO + ((size_t)(b * NRES + jc)) * 3;
    pox[q] = o[0]; poy[q] = o[1]; poz[q] = o[2];
  }

  // wave's 16 gw rows for its i (contiguous 272 float2) -> padded LDS rows
  {
    const float2* src = (const float2*)gw + ((size_t)i * NRES + j0w) * 17;
    float2* wd = (float2*)&wlds[wv][0];
#pragma unroll
    for (int u = 0; u < 5; ++u) {
      const int e = lane + u * 64;
      float2 v = (e < E2) ? src[e] : make_float2(0.f, 0.f);
      if (e < 272) {
        const int row = e / 17, col = e - row * 17;
        wd[row * 18 + col] = v;
      }
    }
  }
  // my j's weights: 9 x ds_read_b128 (in-wave DS ordering; no barrier needed)
  float w[36];
  {
    const float4* wp = (const float4*)&wlds[wv][jsub * 36];
#pragma unroll
    for (int k4 = 0; k4 < 9; ++k4) {
      float4 v = wp[k4];
      w[4*k4+0] = v.x; w[4*k4+1] = v.y; w[4*k4+2] = v.z; w[4*k4+3] = v.w;
    }
    w[34] = 0.f; w[35] = 0.f;
  }

  const float hmn = hmin[i * NRES + jc];
  const float hmx = hmax[i * NRES + jc];

  float acx[5], acy[5], acz[5], aox[5], aoy[5], aoz[5];

#pragma unroll
  for (int q = 0; q < 5; ++q) {
    const int b = bsub * 5 + q;
    const float* pi = &sIC[(b * 2 + h) * 4];
    const float* ph = &sHH[(b * 2 + h) * 4];

    // ---- CB distogram: 3 x 12-bin ratio-recurrence, 4 exps ----
    float dx = pjx[q] - pi[0], dy = pjy[q] - pi[1], dz = pjz[q] - pi[2];
    float d2 = fmaf(dx, dx, fmaf(dy, dy, dz * dz));
    d2 = fminf(fmaxf(d2, 0.01f), 1600.0f);          // d in [0.1, 40]
    float rinv = __frsqrt_rn(d2);
    float d    = d2 * rinv;
    float dA = d - 3.75f, dB = d - 9.75f, dC = d - 15.75f;
    float gA = EXP2F(-0.46166241f * dA * dA);
    float gB = EXP2F(-0.46166241f * dB * dB);
    float gC = EXP2F(-0.46166241f * dC * dC);
    float mA = EXP2F(fmaf(0.46166241f, dA, -0.11541560f));
    float mB = mA * 0.14660697f;                    // * e^-1.92
    float mC = mA * 0.02149329f;                    // * e^-3.84
    float s0 = 0.f, s1 = 0.f, s2 = 0.f;
#pragma unroll
    for (int k = 0; k < 12; ++k) {
      s0 = fmaf(w[k]      * dA, gA, s0); gA *= mA; mA *= 0.85214379f; dA -= 0.5f;
      s1 = fmaf(w[k + 12] * dB, gB, s1); gB *= mB; mB *= 0.85214379f; dB -= 0.5f;
      s2 = fmaf(w[k + 24] * dC, gC, s2); gC *= mC; mC *= 0.85214379f; dC -= 0.5f;
    }
    float cf = 76.8f * ((s0 + s1) + s2) * rinv;     // 150 / sigma^3
    acx[q] = cf * dx; acy[q] = cf * dy; acz[q] = cf * dz;

    // ---- HB restraint (O_j - H_i) ----
    float ex = pox[q] - ph[0], ey = poy[q] - ph[1], ez = poz[q] - ph[2];
    float e2 = fmaf(ex, ex, fmaf(ey, ey, ez * ez));
    e2 = fminf(fmaxf(e2, 0.01f), 1600.0f);
    float rh = __frsqrt_rn(e2);
    float dh = e2 * rh;
    float vmin = fmaxf(hmn - dh, 0.0f);
    float vmax = fmaxf(dh - hmx, 0.0f);
    float fmn = 15.0f * vmin;                       // 3*5*v^1
    float fmx = (vmax > 0.0f) ? 5.0f * EXP2F(0.75f * LOG2F(vmax)) : 0.0f;
    float ff = (fmn - fmx) * rh;
    float qx = ff * ex, qy = ff * ey, qz = ff * ez; // pair_hb
    aox[q] = qx; aoy[q] = qy; aoz[q] = qz;

    // accs_H[b,i] = -sum_j pair_hb: 16-lane group sum, one plain store
    float sx = g16sum(jv ? qx : 0.f);
    float sy = g16sum(jv ? qy : 0.f);
    float sz = g16sum(jv ? qz : 0.f);
    if (jsub == 0) {
      if constexpr (PART) {
        float* hp = part + (size_t)(OFF_H + jt * 4 + s) * PLANE +
                    ((size_t)b * NRES + i) * 3;
        hp[0] = -sx; hp[1] = -sy; hp[2] = -sz;      // h-halves: disjoint cells
      } else {
        atomicAdd(&out[4 * PLANE + (b * NRES + i) * 3 + 0], -sx);
        atomicAdd(&out[4 * PLANE + (b * NRES + i) * 3 + 1], -sy);
        atomicAdd(&out[4 * PLANE + (b * NRES + i) * 3 + 2], -sz);
      }
    }
  }

  if constexpr (PART) {
    // combine the two i-halves via LDS, then plain stores (single writer/cell)
    if (h == 0) {
      float* cb = &cbuf[s][lane][0];
#pragma unroll
      for (int q = 0; q < 5; ++q) {
        cb[q]      = acx[q]; cb[5  + q] = acy[q]; cb[10 + q] = acz[q];
        cb[15 + q] = aox[q]; cb[20 + q] = aoy[q]; cb[25 + q] = aoz[q];
      }
    }
    __syncthreads();
    if (h == 1 && jv) {
      const float* cb = &cbuf[s][lane][0];
      float* pc  = part + (size_t)ch * PLANE;
      float* po2 = part + (size_t)(OFF_O + ch) * PLANE;
#pragma unroll
      for (int q = 0; q < 5; ++q) {
        const int base = ((bsub * 5 + q) * NRES + j) * 3;
        pc[base + 0]  = acx[q] + cb[q];
        pc[base + 1]  = acy[q] + cb[5 + q];
        pc[base + 2]  = acz[q] + cb[10 + q];
        po2[base + 0] = aox[q] + cb[15 + q];
        po2[base + 1] = aoy[q] + cb[20 + q];
        po2[base + 2] = aoz[q] + cb[25 + q];
      }
    }
  } else {
    if (jv) {
#pragma unroll
      for (int q = 0; q < 5; ++q) {
        const int base = ((bsub * 5 + q) * NRES + j) * 3;
        atomicAdd(&out[3 * PLANE + base + 0], acx[q]);
        atomicAdd(&out[3 * PLANE + base + 1], acy[q]);
        atomicAdd(&out[3 * PLANE + base + 2], acz[q]);
        atomicAdd(&out[2 * PLANE + base + 0], aox[q]);
        atomicAdd(&out[2 * PLANE + base + 1], aoy[q]);
        atomicAdd(&out[2 * PLANE + base + 2], aoz[q]);
      }
    }
  }
}

// 13 segments x NRED blocks: segs 0-5 CB (25 planes each, atomicAdd),
// 6-11 O (25 each, atomicAdd), 12 H (20 planes, plain store).
__global__ __launch_bounds__(256)
void reduce_seg(const float* __restrict__ part, float* __restrict__ out) {
  const int seg = blockIdx.x / NRED;
  const int t   = (blockIdx.x % NRED) * 256 + threadIdx.x;
  if (t >= PLANE) return;

  if (seg < 12) {
    const int c0 = (seg < 6) ? seg * 25 : OFF_O + (seg - 6) * 25;
    const float* p = part + t + (size_t)c0 * PLANE;
    float s[5] = {};
#pragma unroll
    for (int c = 0; c < 25; c += 5) {
#pragma unroll
      for (int u = 0; u < 5; ++u) s[u] += p[(size_t)(c + u) * PLANE];
    }
    const float tot = ((s[0] + s[1]) + (s[2] + s[3])) + s[4];
    atomicAdd(&out[((seg < 6) ? 3 : 2) * PLANE + t], tot);
  } else {
    const float* p = part + t + (size_t)OFF_H * PLANE;
    float s[5] = {};
#pragma unroll
    for (int c = 0; c < 20; c += 5) {
#pragma unroll
      for (int u = 0; u < 5; ++u) s[u] += p[(size_t)(c + u) * PLANE];
    }
    out[4 * PLANE + t] = ((s[0] + s[1]) + (s[2] + s[3])) + s[4];
  }
}

extern "C" void kernel_launch(void* const* d_in, const int* in_sizes, int n_in,
                              void* d_out, int out_size, void* d_ws, size_t ws_size,
                              hipStream_t stream) {
  // input order per setup_inputs(): N, C, O, CB, H, gaussian_weights, hb_min, hb_max
  const float* cO  = (const float*)d_in[2];
  const float* cCB = (const float*)d_in[3];
  const float* cH  = (const float*)d_in[4];
  const float* gw  = (const float*)d_in[5];
  const float* hmn = (const float*)d_in[6];
  const float* hmx = (const float*)d_in[7];
  float* out  = (float*)d_out;
  float* part = (float*)d_ws;

  // out zeroed every call: N,C planes are exactly 0 (K_ANG_HB_GEN == 0);
  // CB/O planes are atomic-accumulated by reduce_seg.
  (void)hipMemsetAsync(out, 0, (size_t)out_size * sizeof(float), stream);

  if (ws_size >= (size_t)NPL * PLANE * sizeof(float)) {      // 23.04 MB
    force_fused<true><<<dim3(5 * NCH), dim3(512), 0, stream>>>(
        cO, cCB, cH, gw, hmn, hmx, out, part);
    reduce_seg<<<dim3(13 * NRED), dim3(256), 0, stream>>>(part, out);
  } else {
    force_fused<false><<<dim3(5 * NCH), dim3(512), 0, stream>>>(
        cO, cCB, cH, gw, hmn, hmx, out, nullptr);
  }
}